// Round 1
// baseline (85.979 us; speedup 1.0000x reference)
//
#include <hip/hip_runtime.h>

typedef __attribute__((ext_vector_type(8))) short short8;
typedef __attribute__((ext_vector_type(4))) float f32x4;

__device__ __forceinline__ unsigned short f2bf(float x) {
  unsigned int u = __float_as_uint(x);
  u += 0x7FFFu + ((u >> 16) & 1u);
  return (unsigned short)(u >> 16);
}

// Kernel A: scores[b,t,c] = dot(context(b,t), W[c]) + bias[c]
// via P[t,n] = dot(H[b,t], W'[n]) with n = k3*64+c, W'[n][k] = W[c][k3*512+k]
// scores[t][c] = P[t-1][c] + P[t][64+c] + P[t+1][128+c] + bias[c]
__global__ __launch_bounds__(512) void crf_scores_kernel(
    const float* __restrict__ H, const float* __restrict__ W,
    const float* __restrict__ bias, float* __restrict__ scores)
{
  // union: staging tiles (A 16KB + B 24KB) then P[128][196] f32 (100352 B)
  __shared__ __align__(16) float smem[25088];
  unsigned char* aT = (unsigned char*)smem;           // [128 rows][128 B]
  unsigned char* bT = ((unsigned char*)smem) + 16384; // [192 rows][128 B]
  float* P = smem;                                    // [128][196]

  const int b    = blockIdx.x;
  const int tid  = threadIdx.x;
  const int lane = tid & 63;
  const int wid  = tid >> 6;   // 0..7
  const int wm   = wid >> 2;   // 0..1  (rows 64*wm .. +63)
  const int wn   = wid & 3;    // 0..3  (cols 48*wn .. +47)

  f32x4 acc[4][3] = {};

  const float* Hb = H + (size_t)b * (128 * 512);

  for (int kk = 0; kk < 512; kk += 64) {
    // stage A tile: H[b, 0:128, kk:kk+64] -> bf16 LDS, XOR-swizzled
    #pragma unroll
    for (int it = 0; it < 4; ++it) {
      int i = it * 512 + tid;        // 0..2047
      int row = i >> 4, k4 = i & 15; // 16 float4 per row
      float4 v = ((const float4*)(Hb + row * 512 + kk))[k4];
      ushort4 pkt;
      pkt.x = f2bf(v.x); pkt.y = f2bf(v.y); pkt.z = f2bf(v.z); pkt.w = f2bf(v.w);
      *(ushort4*)(aT + row * 128 + ((k4 * 8) ^ ((row & 7) << 4))) = pkt;
    }
    // stage B tile: W'[0:192, kk:kk+64] -> bf16 LDS, XOR-swizzled
    #pragma unroll
    for (int it = 0; it < 6; ++it) {
      int i = it * 512 + tid;        // 0..3071
      int n = i >> 4, k4 = i & 15;
      float4 v = ((const float4*)(W + (n & 63) * 1536 + (n >> 6) * 512 + kk))[k4];
      ushort4 pkt;
      pkt.x = f2bf(v.x); pkt.y = f2bf(v.y); pkt.z = f2bf(v.z); pkt.w = f2bf(v.w);
      *(ushort4*)(bT + n * 128 + ((k4 * 8) ^ ((n & 7) << 4))) = pkt;
    }
    __syncthreads();
    #pragma unroll
    for (int ks = 0; ks < 2; ++ks) {
      const int kbyte = ks * 64 + ((lane >> 4) << 4);
      short8 af[4], bfr[3];
      #pragma unroll
      for (int m = 0; m < 4; ++m) {
        int row = wm * 64 + m * 16 + (lane & 15);
        af[m] = *(const short8*)(aT + row * 128 + (kbyte ^ ((row & 7) << 4)));
      }
      #pragma unroll
      for (int n = 0; n < 3; ++n) {
        int col = wn * 48 + n * 16 + (lane & 15);
        bfr[n] = *(const short8*)(bT + col * 128 + (kbyte ^ ((col & 7) << 4)));
      }
      #pragma unroll
      for (int m = 0; m < 4; ++m) {
        #pragma unroll
        for (int n = 0; n < 3; ++n) {
          asm("v_mfma_f32_16x16x32_bf16 %0, %1, %2, %0"
              : "+v"(acc[m][n]) : "v"(af[m]), "v"(bfr[n]));
        }
      }
    }
    __syncthreads();
  }

  // acc -> P in LDS. C/D layout: col = lane&15, row = 4*(lane>>4)+j (m89-verified)
  #pragma unroll
  for (int m = 0; m < 4; ++m) {
    #pragma unroll
    for (int n = 0; n < 3; ++n) {
      int row0 = wm * 64 + m * 16 + ((lane >> 4) << 2);
      int col  = wn * 48 + n * 16 + (lane & 15);
      #pragma unroll
      for (int j = 0; j < 4; ++j)
        P[(row0 + j) * 196 + col] = acc[m][n][j];
    }
  }
  __syncthreads();

  // scores epilogue
  float* outb = scores + (size_t)b * (128 * 64);
  #pragma unroll
  for (int it = 0; it < 4; ++it) {
    int i4 = it * 512 + tid;       // 0..2047
    int t = i4 >> 4, c4 = i4 & 15; // 16 float4 per t-row
    float4 s = *(const float4*)(P + t * 196 + 64 + c4 * 4);
    float4 bb = ((const float4*)bias)[c4];
    s.x += bb.x; s.y += bb.y; s.z += bb.z; s.w += bb.w;
    if (t > 0) {
      float4 g = *(const float4*)(P + (t - 1) * 196 + c4 * 4);
      s.x += g.x; s.y += g.y; s.z += g.z; s.w += g.w;
    }
    if (t < 127) {
      float4 g = *(const float4*)(P + (t + 1) * 196 + 128 + c4 * 4);
      s.x += g.x; s.y += g.y; s.z += g.z; s.w += g.w;
    }
    *(float4*)(outb + t * 64 + c4 * 4) = s;
  }
}

// Kernel B: per-batch numerator + forward algorithm (exp-space matvec scan)
__global__ __launch_bounds__(64) void crf_ll_kernel(
    const float* __restrict__ scores,
    const float* __restrict__ startT, const float* __restrict__ endT,
    const float* __restrict__ trans,
    const int* __restrict__ y, const int* __restrict__ y_len,
    float* __restrict__ out)
{
  __shared__ __align__(16) float sc[128][64]; // this batch's scores, 32KB
  __shared__ __align__(16) float ubuf[64];
  const int b = blockIdx.x;
  const int lane = threadIdx.x; // = destination state c'

  // stage scores[b]
  const float4* src = (const float4*)(scores + (size_t)b * 8192);
  float4* dst = (float4*)(&sc[0][0]);
  for (int it = 0; it < 32; ++it) dst[it * 64 + lane] = src[it * 64 + lane];

  // E column for this lane: E[c][lane] = exp(trans[c][lane]) in registers
  float e[64];
  #pragma unroll
  for (int c = 0; c < 64; ++c) e[c] = __expf(trans[c * 64 + lane]);

  const int len = y_len[b];
  const int* yb = y + b * 128;
  __syncthreads();

  // --- numerator ---
  float p = 0.f;
  #pragma unroll
  for (int rep = 0; rep < 2; ++rep) {
    int t = lane + rep * 64;
    if (t < 127) {
      int yt = yb[t], yt1 = yb[t + 1];
      if (t < len)     p += sc[t][yt];                // emission, mask[t]
      if (t + 1 < len) p += trans[yt * 64 + yt1];     // transition, mask[t+1]
    }
  }
  #pragma unroll
  for (int s = 32; s > 0; s >>= 1) p += __shfl_xor(p, s, 64);
  float num = p + startT[yb[0]] + endT[yb[len - 1]];
  if (len == 128) num += sc[127][yb[127]];            // mask[:, -1] term

  // --- forward scan ---
  float lp = startT[lane] + sc[0][lane];
  for (int t = 1; t < 128; ++t) {
    float m = lp;
    #pragma unroll
    for (int s = 32; s > 0; s >>= 1) m = fmaxf(m, __shfl_xor(m, s, 64));
    ubuf[lane] = __expf(lp - m);
    __syncthreads();
    float v = 0.f;
    const float4* u4 = (const float4*)ubuf;
    #pragma unroll
    for (int cc = 0; cc < 16; ++cc) {
      float4 uu = u4[cc];
      v = fmaf(uu.x, e[4 * cc + 0], v);
      v = fmaf(uu.y, e[4 * cc + 1], v);
      v = fmaf(uu.z, e[4 * cc + 2], v);
      v = fmaf(uu.w, e[4 * cc + 3], v);
    }
    float lpn = __logf(v) + m + sc[t][lane];
    lp = (t < len) ? lpn : lp;
    __syncthreads();
  }
  float x = lp + endT[lane];
  float mm = x;
  #pragma unroll
  for (int s = 32; s > 0; s >>= 1) mm = fmaxf(mm, __shfl_xor(mm, s, 64));
  float se = __expf(x - mm);
  #pragma unroll
  for (int s = 32; s > 0; s >>= 1) se += __shfl_xor(se, s, 64);
  if (lane == 0) out[b] = num - (mm + __logf(se));
}

extern "C" void kernel_launch(void* const* d_in, const int* in_sizes, int n_in,
                              void* d_out, int out_size, void* d_ws, size_t ws_size,
                              hipStream_t stream) {
  const float* H      = (const float*)d_in[0];
  const float* W      = (const float*)d_in[1];
  const float* bias   = (const float*)d_in[2];
  const float* startT = (const float*)d_in[3];
  const float* endT   = (const float*)d_in[4];
  const float* trans  = (const float*)d_in[5];
  const int*   y      = (const int*)d_in[6];
  // d_in[7] = y_mask (implied by y_len; unused)
  const int*   y_len  = (const int*)d_in[8];
  float* out    = (float*)d_out;
  float* scores = (float*)d_ws; // 256*128*64 f32 = 8.39 MB

  crf_scores_kernel<<<dim3(256), dim3(512), 0, stream>>>(H, W, bias, scores);
  crf_ll_kernel<<<dim3(256), dim3(64), 0, stream>>>(scores, startT, endT, trans, y, y_len, out);
}

// Round 2
// 71.236 us; speedup vs baseline: 1.2070x; 1.2070x over previous
//
#include <hip/hip_runtime.h>

typedef __attribute__((ext_vector_type(8))) short short8;
typedef __attribute__((ext_vector_type(4))) float f32x4;

__device__ __forceinline__ unsigned short f2bf(float x) {
  unsigned int u = __float_as_uint(x);
  u += 0x7FFFu + ((u >> 16) & 1u);
  return (unsigned short)(u >> 16);
}

// Fused: per-batch context-GEMM (bf16 MFMA) -> scores in LDS -> numerator +
// forward-scan logZ, all in one block (256 blocks, 512 threads, 1 block/CU).
__global__ __launch_bounds__(512) void crf_fused_kernel(
    const float* __restrict__ H, const float* __restrict__ W,
    const float* __restrict__ bias,
    const float* __restrict__ startT, const float* __restrict__ endT,
    const float* __restrict__ trans,
    const int* __restrict__ y, const int* __restrict__ y_len,
    float* __restrict__ out)
{
  // union: staging tiles (A 16KB @0, B 24KB @16K) then P[128][196] f32
  __shared__ __align__(16) float smem[25088];     // 100352 B
  __shared__ __align__(16) float sc[128][64];     // 32768 B
  __shared__ __align__(16) float ubuf[64];
  unsigned char* aT = (unsigned char*)smem;           // [128 rows][128 B]
  unsigned char* bT = ((unsigned char*)smem) + 16384; // [192 rows][128 B]
  float* P = smem;                                    // [128][196]

  const int b    = blockIdx.x;
  const int tid  = threadIdx.x;
  const int lane = tid & 63;
  const int wid  = tid >> 6;   // 0..7
  const int wm   = wid >> 2;   // 0..1
  const int wn   = wid & 3;    // 0..3

  f32x4 acc[4][3] = {};
  const float* Hb = H + (size_t)b * (128 * 512);

  // ---- GEMM: P[t,n] = dot(H[b,t,:], W'[n,:]) over K=512, bf16 MFMA ----
  float4 areg[4], breg[6];
  int aRow[4], aK4[4], bN[6], bK4[6];
  #pragma unroll
  for (int it = 0; it < 4; ++it) {
    int i = it * 512 + tid; aRow[it] = i >> 4; aK4[it] = i & 15;
  }
  #pragma unroll
  for (int it = 0; it < 6; ++it) {
    int i = it * 512 + tid; bN[it] = i >> 4; bK4[it] = i & 15;
  }

  #pragma unroll
  for (int it = 0; it < 4; ++it)
    areg[it] = ((const float4*)(Hb + aRow[it] * 512 + 0))[aK4[it]];
  #pragma unroll
  for (int it = 0; it < 6; ++it)
    breg[it] = ((const float4*)(W + (bN[it] & 63) * 1536 + (bN[it] >> 6) * 512 + 0))[bK4[it]];

  for (int kk = 0; kk < 512; kk += 64) {
    if (kk) __syncthreads();  // prev tile's LDS reads done
    #pragma unroll
    for (int it = 0; it < 4; ++it) {
      ushort4 pkt;
      pkt.x = f2bf(areg[it].x); pkt.y = f2bf(areg[it].y);
      pkt.z = f2bf(areg[it].z); pkt.w = f2bf(areg[it].w);
      *(ushort4*)(aT + aRow[it] * 128 + ((aK4[it] * 8) ^ ((aRow[it] & 7) << 4))) = pkt;
    }
    #pragma unroll
    for (int it = 0; it < 6; ++it) {
      ushort4 pkt;
      pkt.x = f2bf(breg[it].x); pkt.y = f2bf(breg[it].y);
      pkt.z = f2bf(breg[it].z); pkt.w = f2bf(breg[it].w);
      *(ushort4*)(bT + bN[it] * 128 + ((bK4[it] * 8) ^ ((bN[it] & 7) << 4))) = pkt;
    }
    __syncthreads();
    if (kk < 448) {  // prefetch next K-tile; loads fly during MFMA phase
      #pragma unroll
      for (int it = 0; it < 4; ++it)
        areg[it] = ((const float4*)(Hb + aRow[it] * 512 + kk + 64))[aK4[it]];
      #pragma unroll
      for (int it = 0; it < 6; ++it)
        breg[it] = ((const float4*)(W + (bN[it] & 63) * 1536 + (bN[it] >> 6) * 512 + kk + 64))[bK4[it]];
    }
    #pragma unroll
    for (int ks = 0; ks < 2; ++ks) {
      const int kbyte = ks * 64 + ((lane >> 4) << 4);
      short8 af[4], bfr[3];
      #pragma unroll
      for (int m = 0; m < 4; ++m) {
        int row = wm * 64 + m * 16 + (lane & 15);
        af[m] = *(const short8*)(aT + row * 128 + (kbyte ^ ((row & 7) << 4)));
      }
      #pragma unroll
      for (int n = 0; n < 3; ++n) {
        int col = wn * 48 + n * 16 + (lane & 15);
        bfr[n] = *(const short8*)(bT + col * 128 + (kbyte ^ ((col & 7) << 4)));
      }
      #pragma unroll
      for (int m = 0; m < 4; ++m)
        #pragma unroll
        for (int n = 0; n < 3; ++n)
          asm("v_mfma_f32_16x16x32_bf16 %0, %1, %2, %0"
              : "+v"(acc[m][n]) : "v"(af[m]), "v"(bfr[n]));
    }
  }
  __syncthreads();  // all frag reads done before P overwrites staging

  // acc -> P. C/D layout: col = lane&15, row = 4*(lane>>4)+j
  #pragma unroll
  for (int m = 0; m < 4; ++m)
    #pragma unroll
    for (int n = 0; n < 3; ++n) {
      int row0 = wm * 64 + m * 16 + ((lane >> 4) << 2);
      int col  = wn * 48 + n * 16 + (lane & 15);
      #pragma unroll
      for (int j = 0; j < 4; ++j)
        P[(row0 + j) * 196 + col] = acc[m][n][j];
    }
  __syncthreads();

  // scores epilogue -> LDS sc[t][c]
  #pragma unroll
  for (int it = 0; it < 4; ++it) {
    int i4 = it * 512 + tid;
    int t = i4 >> 4, c4 = i4 & 15;
    float4 s = *(const float4*)(P + t * 196 + 64 + c4 * 4);
    float4 bb = ((const float4*)bias)[c4];
    s.x += bb.x; s.y += bb.y; s.z += bb.z; s.w += bb.w;
    if (t > 0) {
      float4 g = *(const float4*)(P + (t - 1) * 196 + c4 * 4);
      s.x += g.x; s.y += g.y; s.z += g.z; s.w += g.w;
    }
    if (t < 127) {
      float4 g = *(const float4*)(P + (t + 1) * 196 + 128 + c4 * 4);
      s.x += g.x; s.y += g.y; s.z += g.z; s.w += g.w;
    }
    *(float4*)(&sc[t][c4 * 4]) = s;
  }
  __syncthreads();

  if (wid != 0) return;  // no barriers below: waves 1-7 may exit

  // ---- wave 0: numerator + forward scan (lane = destination state) ----
  const int len = y_len[b];
  const int* yb = y + b * 128;

  float e[64];
  #pragma unroll
  for (int c = 0; c < 64; ++c) e[c] = __expf(trans[c * 64 + lane]);

  float p = 0.f;
  #pragma unroll
  for (int rep = 0; rep < 2; ++rep) {
    int t = lane + rep * 64;
    if (t < 127) {
      int yt = yb[t], yt1 = yb[t + 1];
      if (t < len)     p += sc[t][yt];
      if (t + 1 < len) p += trans[yt * 64 + yt1];
    }
  }
  #pragma unroll
  for (int s = 32; s > 0; s >>= 1) p += __shfl_xor(p, s, 64);
  float num = p + startT[yb[0]] + endT[yb[len - 1]];
  if (len == 128) num += sc[127][yb[127]];

  // forward scan: shift by lane-0's lp (spread across lanes is ~12, safe)
  float lp = startT[lane] + sc[0][lane];
  for (int t = 1; t < len; ++t) {
    float s = __int_as_float(__builtin_amdgcn_readfirstlane(__float_as_int(lp)));
    ubuf[lane] = __expf(lp - s);
    const float4* u4 = (const float4*)ubuf;  // uniform-addr reads: broadcast
    float vv[8] = {0.f, 0.f, 0.f, 0.f, 0.f, 0.f, 0.f, 0.f};
    #pragma unroll
    for (int i = 0; i < 8; ++i) {
      float4 ua = u4[2 * i], ub = u4[2 * i + 1];
      vv[0] = fmaf(ua.x, e[8 * i + 0], vv[0]);
      vv[1] = fmaf(ua.y, e[8 * i + 1], vv[1]);
      vv[2] = fmaf(ua.z, e[8 * i + 2], vv[2]);
      vv[3] = fmaf(ua.w, e[8 * i + 3], vv[3]);
      vv[4] = fmaf(ub.x, e[8 * i + 4], vv[4]);
      vv[5] = fmaf(ub.y, e[8 * i + 5], vv[5]);
      vv[6] = fmaf(ub.z, e[8 * i + 6], vv[6]);
      vv[7] = fmaf(ub.w, e[8 * i + 7], vv[7]);
    }
    float v = ((vv[0] + vv[1]) + (vv[2] + vv[3])) + ((vv[4] + vv[5]) + (vv[6] + vv[7]));
    lp = __logf(v) + s + sc[t][lane];
  }

  // final logZ with exact max (one-time)
  float x = lp + endT[lane];
  float mm = x;
  #pragma unroll
  for (int s = 32; s > 0; s >>= 1) mm = fmaxf(mm, __shfl_xor(mm, s, 64));
  float se = __expf(x - mm);
  #pragma unroll
  for (int s = 32; s > 0; s >>= 1) se += __shfl_xor(se, s, 64);
  if (lane == 0) out[b] = num - (mm + __logf(se));
}

extern "C" void kernel_launch(void* const* d_in, const int* in_sizes, int n_in,
                              void* d_out, int out_size, void* d_ws, size_t ws_size,
                              hipStream_t stream) {
  const float* H      = (const float*)d_in[0];
  const float* W      = (const float*)d_in[1];
  const float* bias   = (const float*)d_in[2];
  const float* startT = (const float*)d_in[3];
  const float* endT   = (const float*)d_in[4];
  const float* trans  = (const float*)d_in[5];
  const int*   y      = (const int*)d_in[6];
  const int*   y_len  = (const int*)d_in[8];
  float* out = (float*)d_out;

  crf_fused_kernel<<<dim3(256), dim3(512), 0, stream>>>(
      H, W, bias, startT, endT, trans, y, y_len, out);
}